// Round 3
// baseline (296.057 us; speedup 1.0000x reference)
//
#include <hip/hip_runtime.h>
#include <stdint.h>

// Self-attention, B=8 S=2048 D=E=512, fp32 in/out, bf16 MFMA internally.
//   xconv:    x fp32 -> bf16
//   wconv:    W[k][n] fp32 -> Wt[n][k] bf16 (x3), LDS-tiled transpose
//   qkv_gemm: m97-style async-staged GEMM; Q row-major bf16;
//             K in [B][s/32][e/16][32s][16e] 1KB tiles; V in [B][e/32][s/16][32e][16s] 1KB tiles
//   attn:     v4: 32x32x16 MFMA everywhere. 64 Q-rows/block, 512 thr, 256 blocks (1/CU,
//             b=blk&7 XCD-pins K/V). Q staged ONCE in LDS (swizzled); K,V stream
//             global->reg as coalesced 1KB fragments. P double-buffered in LDS ->
//             ONE barrier per 256-key iteration. No global_load_lds, no DMA hazards.

using f32x4  = __attribute__((ext_vector_type(4))) float;
using f32x16 = __attribute__((ext_vector_type(16))) float;
using s16x8  = __attribute__((ext_vector_type(8))) short;
using u16x4  = __attribute__((ext_vector_type(4))) unsigned short;

#define S_LEN 2048
#define EMB   512

#define ASYNC16(g, l)                                                     \
  __builtin_amdgcn_global_load_lds(                                       \
      (const __attribute__((address_space(1))) void*)(g),                 \
      (__attribute__((address_space(3))) void*)(l), 16, 0, 0)

__device__ __forceinline__ unsigned short f2bf(float f) {
  union { float f; unsigned u; } v; v.f = f;
  unsigned r = v.u + 0x7fffu + ((v.u >> 16) & 1u);   // RNE
  return (unsigned short)(r >> 16);
}

// ---------------- kernel 0: x fp32 -> bf16 ----------------
__global__ __launch_bounds__(256) void xconv_kernel(
    const float* __restrict__ x, short* __restrict__ xb) {
  int i = (blockIdx.x * 256 + threadIdx.x) * 8;
  f32x4 a = *(const f32x4*)(x + i);
  f32x4 b = *(const f32x4*)(x + i + 4);
  s16x8 h;
  h[0] = (short)f2bf(a[0]); h[1] = (short)f2bf(a[1]);
  h[2] = (short)f2bf(a[2]); h[3] = (short)f2bf(a[3]);
  h[4] = (short)f2bf(b[0]); h[5] = (short)f2bf(b[1]);
  h[6] = (short)f2bf(b[2]); h[7] = (short)f2bf(b[3]);
  *(s16x8*)(xb + i) = h;
}

// ---------------- kernel 1: weight transpose (LDS-tiled, coalesced) ----------------
// grid = 3 mats * 64 tiles of 64x64.
__global__ __launch_bounds__(256) void wconv_kernel(
    const float* __restrict__ Wq, const float* __restrict__ Wk,
    const float* __restrict__ Wv, short* __restrict__ Wt) {
  __shared__ float T[64][65];
  int bid = blockIdx.x;
  int mat = bid >> 6;
  int t   = bid & 63;
  int k0  = (t & 7) << 6, n0 = (t >> 3) << 6;
  const float* W = (mat == 0) ? Wq : (mat == 1) ? Wk : Wv;
  int tid = threadIdx.x;
  int rr = tid >> 4, cc = tid & 15;
#pragma unroll
  for (int p = 0; p < 4; ++p) {
    int row = p * 16 + rr;
    f32x4 v = *(const f32x4*)(W + (size_t)(k0 + row) * 512 + n0 + cc * 4);
#pragma unroll
    for (int j = 0; j < 4; ++j) T[row][cc * 4 + j] = v[j];
  }
  __syncthreads();
  short* D = Wt + (size_t)mat * 262144;
#pragma unroll
  for (int p = 0; p < 4; ++p) {
    int nrow = p * 16 + rr;
    u16x4 h;
#pragma unroll
    for (int j = 0; j < 4; ++j) h[j] = f2bf(T[cc * 4 + j][nrow]);
    *(u16x4*)(D + (size_t)(n0 + nrow) * 512 + k0 + cc * 4) = h;
  }
}

// ---------------- kernel 2: QKV projection GEMM (m97 structure) ----------------
__global__ __launch_bounds__(256) void qkv_gemm(
    const short* __restrict__ xb, const short* __restrict__ Wt,
    const float* __restrict__ bq, const float* __restrict__ bk,
    const float* __restrict__ bv,
    short* __restrict__ Qg, short* __restrict__ Kg, short* __restrict__ VTg) {
  __shared__ __align__(16) short As[128 * 64];   // 16B chunk c stored at c^(row&7)
  __shared__ __align__(16) short Bs[128 * 64];
  int gid = blockIdx.x;
  int mat = gid >> 9;
  int rem = gid & 511;
  int mt  = rem & 127, nt = rem >> 7;
  int m0  = mt << 7,   n0 = nt << 7;
  const short* W    = Wt + (size_t)mat * 262144;
  const float* bias = (mat == 0) ? bq : (mat == 1) ? bk : bv;

  int tid = threadIdx.x, lane = tid & 63, wv = tid >> 6;
  int l16 = lane & 15, quad = lane >> 4;
  int wr = (wv & 1) << 6, wc = (wv >> 1) << 6;
  int drow = lane >> 3;
  int dchk = (lane & 7) ^ drow;

  const f32x4 Z4 = {0.f, 0.f, 0.f, 0.f};
  f32x4 acc[4][4];
#pragma unroll
  for (int a = 0; a < 4; ++a)
#pragma unroll
    for (int c = 0; c < 4; ++c) acc[a][c] = Z4;

  for (int it = 0; it < 8; ++it) {
    int k0 = it << 6;
    __syncthreads();
#pragma unroll
    for (int i = 0; i < 4; ++i) {
      int g   = wv * 4 + i;
      int row = g * 8 + drow;
      ASYNC16(xb + (size_t)(m0 + row) * 512 + k0 + dchk * 8, &As[g * 512]);
    }
#pragma unroll
    for (int i = 0; i < 4; ++i) {
      int g   = wv * 4 + i;
      int row = g * 8 + drow;
      ASYNC16(W + (size_t)(n0 + row) * 512 + k0 + dchk * 8, &Bs[g * 512]);
    }
    __syncthreads();
#pragma unroll
    for (int kk = 0; kk < 2; ++kk) {
      s16x8 af[4], bfr[4];
#pragma unroll
      for (int rb = 0; rb < 4; ++rb) {
        int row = wr + rb * 16 + l16;
        int c   = kk * 4 + quad;
        af[rb] = *(const s16x8*)(As + row * 64 + ((c ^ (row & 7)) * 8));
      }
#pragma unroll
      for (int cb = 0; cb < 4; ++cb) {
        int row = wc + cb * 16 + l16;
        int c   = kk * 4 + quad;
        bfr[cb] = *(const s16x8*)(Bs + row * 64 + ((c ^ (row & 7)) * 8));
      }
#pragma unroll
      for (int rb = 0; rb < 4; ++rb)
#pragma unroll
        for (int cb = 0; cb < 4; ++cb)
          acc[rb][cb] = __builtin_amdgcn_mfma_f32_16x16x32_bf16(af[rb], bfr[cb], acc[rb][cb], 0, 0, 0);
    }
  }

  float bsv[4];
#pragma unroll
  for (int cb = 0; cb < 4; ++cb) bsv[cb] = bias[n0 + wc + cb * 16 + l16];

  if (mat == 0) {
#pragma unroll
    for (int rb = 0; rb < 4; ++rb)
#pragma unroll
      for (int cb = 0; cb < 4; ++cb)
#pragma unroll
        for (int r = 0; r < 4; ++r) {
          int m = m0 + wr + rb * 16 + quad * 4 + r;
          Qg[(size_t)m * 512 + n0 + wc + cb * 16 + l16] =
              (short)f2bf(acc[rb][cb][r] + bsv[cb]);
        }
  } else if (mat == 1) {
    // K tiles: [bb][s>>5][e>>4][(s&31)*16 + (e&15)]
#pragma unroll
    for (int rb = 0; rb < 4; ++rb)
#pragma unroll
      for (int cb = 0; cb < 4; ++cb)
#pragma unroll
        for (int r = 0; r < 4; ++r) {
          int m  = m0 + wr + rb * 16 + quad * 4 + r;
          int bb = m >> 11, sl = m & 2047;
          int e  = n0 + wc + cb * 16 + l16;
          size_t idx = (((size_t)bb * 64 + (sl >> 5)) * 32 + (e >> 4)) * 512 +
                       (sl & 31) * 16 + (e & 15);
          Kg[idx] = (short)f2bf(acc[rb][cb][r] + bsv[cb]);
        }
  } else {
    // V tiles: [bb][e>>5][s>>4][(e&31)*16 + (s&15)]
#pragma unroll
    for (int rb = 0; rb < 4; ++rb)
#pragma unroll
      for (int cb = 0; cb < 4; ++cb) {
        u16x4 h;
#pragma unroll
        for (int r = 0; r < 4; ++r) h[r] = f2bf(acc[rb][cb][r] + bsv[cb]);
        int m  = m0 + wr + rb * 16 + quad * 4;
        int bb = m >> 11, sl = m & 2047;
        int e  = n0 + wc + cb * 16 + l16;
        size_t idx = (((size_t)bb * 16 + (e >> 5)) * 128 + (sl >> 4)) * 512 +
                     (e & 31) * 16 + (sl & 15);
        *(u16x4*)(VTg + idx) = h;
      }
  }
}

// ---------------- kernel 3: flash attention v4 (32x32 MFMA, stream K/V) ----------------
// 256 blocks (b=blk&7 -> XCD), 64 Q-rows/block, 8 waves.
// Wave wv owns key-group [wv*32, wv*32+32) of each 256-key iter (K streamed once,
// no duplication) and e-slice [wv*64, wv*64+64) for PV.
// 32x32x16 frag layouts: A: lane l holds A[l&31][8*(l>>5)+j]; B: B[8*(l>>5)+j][l&31];
// C: col=l&31, row=(reg&3)+8*(reg>>2)+4*(l>>5)  [HW-verified m74/m101].
// Hazard ledger (single barrier per iter, Pl double-buffered):
//   P-write(it)->Pl[cur]  ...  barrier(it)  ...  P-read(it)            (RAW ok)
//   P-read(it) before barrier(it+1); P-write(it+2)->Pl[cur] after it   (WAR ok)
__global__ __launch_bounds__(512, 2) void attn_kernel(
    const short* __restrict__ Qg, const short* __restrict__ Kg,
    const short* __restrict__ VTg, float* __restrict__ out) {
  __shared__ __align__(16) short Qs[64 * 512];      // 64 KB, chunk c at c^(row&7)
  __shared__ __align__(16) short Pl[2][64 * 256];   // 2x32 KB, chunk c at c^(row&7)
  __shared__ float lred[8 * 64];
  const float SCL2 = 0.06375871855f;  // log2(e)/sqrt(512)

  int b = blockIdx.x & 7, qt = blockIdx.x >> 3;     // qt 0..31
  int s0 = qt << 6;
  int tid = threadIdx.x, lane = tid & 63, wv = tid >> 6;
  int l5 = lane & 31, hh = lane >> 5;

  const short* Qb = Qg  + ((size_t)b * S_LEN + s0) * 512;
  const short* Kb = Kg  + (size_t)b * 1048576;      // [s/32][e/16] 1KB tiles
  const short* Vb = VTg + (size_t)b * 1048576;      // [e/32][s/16] 1KB tiles

  // ---- prologue: Q -> LDS, swizzled ----
#pragma unroll
  for (int i = 0; i < 8; ++i) {
    int row = wv * 8 + i;
    s16x8 v = *(const s16x8*)(Qb + (size_t)row * 512 + lane * 8);
    *(s16x8*)(Qs + row * 512 + ((lane ^ (row & 7)) * 8)) = v;
  }

  const f32x16 Z16 = {0.f,0.f,0.f,0.f,0.f,0.f,0.f,0.f,0.f,0.f,0.f,0.f,0.f,0.f,0.f,0.f};
  f32x16 Oa[2][2];
  Oa[0][0] = Z16; Oa[0][1] = Z16; Oa[1][0] = Z16; Oa[1][1] = Z16;
  float lsum[2][16];
#pragma unroll
  for (int rg = 0; rg < 2; ++rg)
#pragma unroll
    for (int r = 0; r < 16; ++r) lsum[rg][r] = 0.f;

  int fragoff = l5 * 16 + hh * 8;                   // lane offset within 1KB tile
  int swz0 = l5 & 7;                                // (row&7) for rg0 and rg1 (32+l5)

  __syncthreads();                                  // Qs ready

  for (int it = 0; it < 8; ++it) {
    int cur = it & 1;

    // ---- QK: S[64 rows x 32 keys(wv-group)], K streamed global->reg ----
    f32x16 S0 = Z16, S1 = Z16;
    const short* kbase = Kb + (size_t)((it * 8 + wv) * 32) * 512 + fragoff;
    s16x8 kf[8];
#pragma unroll
    for (int ks = 0; ks < 8; ++ks) kf[ks] = *(const s16x8*)(kbase + ks * 512);
#pragma unroll
    for (int ks = 0; ks < 32; ++ks) {
      int ch = ((ks * 2 + hh) ^ swz0) * 8;
      s16x8 qa0 = *(const s16x8*)(Qs + l5 * 512 + ch);
      s16x8 qa1 = *(const s16x8*)(Qs + (32 + l5) * 512 + ch);
      S0 = __builtin_amdgcn_mfma_f32_32x32x16_bf16(qa0, kf[ks & 7], S0, 0, 0, 0);
      S1 = __builtin_amdgcn_mfma_f32_32x32x16_bf16(qa1, kf[ks & 7], S1, 0, 0, 0);
      if (ks < 24) kf[ks & 7] = *(const s16x8*)(kbase + (ks + 8) * 512);
    }

    // ---- no-max softmax; write P (swizzled) ----
    short* Pc = &Pl[cur][0];
#pragma unroll
    for (int r = 0; r < 16; ++r) {
      int rbase = (r & 3) + 8 * (r >> 2) + 4 * hh;
      int chunk = wv * 4 + (l5 >> 3);
      {
        float p = exp2f(S0[r] * SCL2);
        lsum[0][r] += p;
        int prow = rbase;
        Pc[prow * 256 + ((chunk ^ (prow & 7)) * 8) + (l5 & 7)] = (short)f2bf(p);
      }
      {
        float p = exp2f(S1[r] * SCL2);
        lsum[1][r] += p;
        int prow = 32 + rbase;
        Pc[prow * 256 + ((chunk ^ (prow & 7)) * 8) + (l5 & 7)] = (short)f2bf(p);
      }
    }

    __syncthreads();   // single per-iter barrier: P(it) visible; P(it-1) WAR safe

    // ---- PV: O[64 x 64e-slice] += P[64x256] @ V[256 x 64e], V streamed ----
    const short* vb0 = Vb + (size_t)((wv * 2 + 0) * 128 + it * 16) * 512 + fragoff;
    const short* vb1 = Vb + (size_t)((wv * 2 + 1) * 128 + it * 16) * 512 + fragoff;
    s16x8 vf[8];
#pragma unroll
    for (int k4 = 0; k4 < 4; ++k4) {
      vf[k4 * 2]     = *(const s16x8*)(vb0 + k4 * 512);
      vf[k4 * 2 + 1] = *(const s16x8*)(vb1 + k4 * 512);
    }
#pragma unroll
    for (int ks = 0; ks < 16; ++ks) {
      int ch = ((ks * 2 + hh) ^ swz0) * 8;
      s16x8 pa0 = *(const s16x8*)(Pc + l5 * 256 + ch);
      s16x8 pa1 = *(const s16x8*)(Pc + (32 + l5) * 256 + ch);
      Oa[0][0] = __builtin_amdgcn_mfma_f32_32x32x16_bf16(pa0, vf[(ks & 3) * 2], Oa[0][0], 0, 0, 0);
      Oa[1][0] = __builtin_amdgcn_mfma_f32_32x32x16_bf16(pa1, vf[(ks & 3) * 2], Oa[1][0], 0, 0, 0);
      Oa[0][1] = __builtin_amdgcn_mfma_f32_32x32x16_bf16(pa0, vf[(ks & 3) * 2 + 1], Oa[0][1], 0, 0, 0);
      Oa[1][1] = __builtin_amdgcn_mfma_f32_32x32x16_bf16(pa1, vf[(ks & 3) * 2 + 1], Oa[1][1], 0, 0, 0);
      if (ks < 12) {
        vf[(ks & 3) * 2]     = *(const s16x8*)(vb0 + (ks + 4) * 512);
        vf[(ks & 3) * 2 + 1] = *(const s16x8*)(vb1 + (ks + 4) * 512);
      }
    }
    // no second barrier: Pl double-buffered (ledger above)
  }

  // ---- epilogue: row-sum reduce (cols live on l5), combine waves, store ----
#pragma unroll
  for (int rg = 0; rg < 2; ++rg)
#pragma unroll
    for (int r = 0; r < 16; ++r) {
      float v = lsum[rg][r];
      v += __shfl_xor(v, 1);
      v += __shfl_xor(v, 2);
      v += __shfl_xor(v, 4);
      v += __shfl_xor(v, 8);
      v += __shfl_xor(v, 16);
      lsum[rg][r] = v;               // sum over this wave's 32 keys-group
    }
  if (l5 == 0) {
#pragma unroll
    for (int rg = 0; rg < 2; ++rg)
#pragma unroll
      for (int r = 0; r < 16; ++r)
        lred[wv * 64 + rg * 32 + (r & 3) + 8 * (r >> 2) + 4 * hh] = lsum[rg][r];
  }
  __syncthreads();
  if (tid < 64) {
    float t = 0.f;
#pragma unroll
    for (int w = 0; w < 8; ++w) t += lred[w * 64 + tid];
    lred[tid] = 1.0f / t;
  }
  __syncthreads();

  float* ob = out + ((size_t)b * S_LEN + s0) * 512;
#pragma unroll
  for (int rg = 0; rg < 2; ++rg)
#pragma unroll
    for (int r = 0; r < 16; ++r) {
      int row = rg * 32 + (r & 3) + 8 * (r >> 2) + 4 * hh;
      float li = lred[row];
      ob[(size_t)row * 512 + wv * 64 + l5]      = Oa[rg][0][r] * li;
      ob[(size_t)row * 512 + wv * 64 + 32 + l5] = Oa[rg][1][r] * li;
    }
}

// ---------------- host launch ----------------
extern "C" void kernel_launch(void* const* d_in, const int* in_sizes, int n_in,
                              void* d_out, int out_size, void* d_ws, size_t ws_size,
                              hipStream_t stream) {
  const float* x  = (const float*)d_in[0];
  const float* Wq = (const float*)d_in[1];
  const float* bq = (const float*)d_in[2];
  const float* Wk = (const float*)d_in[3];
  const float* bk = (const float*)d_in[4];
  const float* Wv = (const float*)d_in[5];
  const float* bv = (const float*)d_in[6];

  short* Wt  = (short*)d_ws;
  short* xb  = (short*)((char*)d_ws + 1572864);
  short* Qg  = xb + (size_t)8388608;
  short* Kg  = Qg + (size_t)8388608;
  short* VTg = Kg + (size_t)8388608;

  xconv_kernel<<<4096, 256, 0, stream>>>(x, xb);
  wconv_kernel<<<192, 256, 0, stream>>>(Wq, Wk, Wv, Wt);
  qkv_gemm<<<1536, 256, 0, stream>>>(xb, Wt, bq, bk, bv, Qg, Kg, VTg);
  attn_kernel<<<256, 512, 0, stream>>>(Qg, Kg, VTg, (float*)d_out);
}

// Round 4
// 264.722 us; speedup vs baseline: 1.1184x; 1.1184x over previous
//
#include <hip/hip_runtime.h>
#include <stdint.h>

// Self-attention, B=8 S=2048 D=E=512, fp32 in/out, bf16 MFMA internally.
//   xconv:    x fp32 -> bf16
//   wconv:    W[k][n] fp32 -> Wt[n][k] bf16 (x3), LDS-tiled transpose
//   qkv_gemm: m97-style async-staged GEMM; Q,K row-major bf16; V in 16e x 32s
//             1KB-tiled transposed layout [B][E/16][S/32][16][32] bf16
//   attn v5:  64 Q-rows/block, 8 waves, 256 blocks (1/CU, b=blk&7 XCD-pins K/V).
//             QK waves = 2 row-halves x 4 key-groups: each wave does 32 rows x 16 keys,
//             so K-frags are read HALF as often as v3 (per-key LDS b128: 5 -> 3).
//             Q entirely in registers (qfA/qfB, 128 VGPR; acc in AGPRs).
//             K via swizzled-source DMA->LDS one phase ahead (v3-proven),
//             V 1KB-coalesced tiled global->reg issued at iter top (hidden by QK),
//             P via LDS (stride 72 shorts = 144B: conflict-free b128 reads),
//             64 keys per iteration -> 2 barriers per 64 keys (half of v3).

using f32x4 = __attribute__((ext_vector_type(4))) float;
using s16x8 = __attribute__((ext_vector_type(8))) short;
using u16x4 = __attribute__((ext_vector_type(4))) unsigned short;

#define S_LEN 2048
#define EMB   512

#define ASYNC16(g, l)                                                     \
  __builtin_amdgcn_global_load_lds(                                       \
      (const __attribute__((address_space(1))) void*)(g),                 \
      (__attribute__((address_space(3))) void*)(l), 16, 0, 0)

__device__ __forceinline__ unsigned short f2bf(float f) {
  union { float f; unsigned u; } v; v.f = f;
  unsigned r = v.u + 0x7fffu + ((v.u >> 16) & 1u);   // RNE
  return (unsigned short)(r >> 16);
}

// ---------------- kernel 0: x fp32 -> bf16 ----------------
__global__ __launch_bounds__(256) void xconv_kernel(
    const float* __restrict__ x, short* __restrict__ xb) {
  int i = (blockIdx.x * 256 + threadIdx.x) * 8;
  f32x4 a = *(const f32x4*)(x + i);
  f32x4 b = *(const f32x4*)(x + i + 4);
  s16x8 h;
  h[0] = (short)f2bf(a[0]); h[1] = (short)f2bf(a[1]);
  h[2] = (short)f2bf(a[2]); h[3] = (short)f2bf(a[3]);
  h[4] = (short)f2bf(b[0]); h[5] = (short)f2bf(b[1]);
  h[6] = (short)f2bf(b[2]); h[7] = (short)f2bf(b[3]);
  *(s16x8*)(xb + i) = h;
}

// ---------------- kernel 1: weight transpose (LDS-tiled, coalesced) ----------------
__global__ __launch_bounds__(256) void wconv_kernel(
    const float* __restrict__ Wq, const float* __restrict__ Wk,
    const float* __restrict__ Wv, short* __restrict__ Wt) {
  __shared__ float T[64][65];
  int bid = blockIdx.x;
  int mat = bid >> 6;
  int t   = bid & 63;
  int k0  = (t & 7) << 6, n0 = (t >> 3) << 6;
  const float* W = (mat == 0) ? Wq : (mat == 1) ? Wk : Wv;
  int tid = threadIdx.x;
  int rr = tid >> 4, cc = tid & 15;
#pragma unroll
  for (int p = 0; p < 4; ++p) {
    int row = p * 16 + rr;
    f32x4 v = *(const f32x4*)(W + (size_t)(k0 + row) * 512 + n0 + cc * 4);
#pragma unroll
    for (int j = 0; j < 4; ++j) T[row][cc * 4 + j] = v[j];
  }
  __syncthreads();
  short* D = Wt + (size_t)mat * 262144;
#pragma unroll
  for (int p = 0; p < 4; ++p) {
    int nrow = p * 16 + rr;
    u16x4 h;
#pragma unroll
    for (int j = 0; j < 4; ++j) h[j] = f2bf(T[cc * 4 + j][nrow]);
    *(u16x4*)(D + (size_t)(n0 + nrow) * 512 + k0 + cc * 4) = h;
  }
}

// ---------------- kernel 2: QKV projection GEMM (m97 structure) ----------------
__global__ __launch_bounds__(256) void qkv_gemm(
    const short* __restrict__ xb, const short* __restrict__ Wt,
    const float* __restrict__ bq, const float* __restrict__ bk,
    const float* __restrict__ bv,
    short* __restrict__ Qg, short* __restrict__ Kg, short* __restrict__ VTg) {
  __shared__ __align__(16) short As[128 * 64];   // 16B chunk c stored at c^(row&7)
  __shared__ __align__(16) short Bs[128 * 64];
  int gid = blockIdx.x;
  int mat = gid >> 9;
  int rem = gid & 511;
  int mt  = rem & 127, nt = rem >> 7;
  int m0  = mt << 7,   n0 = nt << 7;
  const short* W    = Wt + (size_t)mat * 262144;
  const float* bias = (mat == 0) ? bq : (mat == 1) ? bk : bv;

  int tid = threadIdx.x, lane = tid & 63, wv = tid >> 6;
  int l16 = lane & 15, quad = lane >> 4;
  int wr = (wv & 1) << 6, wc = (wv >> 1) << 6;
  int drow = lane >> 3;
  int dchk = (lane & 7) ^ drow;

  const f32x4 Z4 = {0.f, 0.f, 0.f, 0.f};
  f32x4 acc[4][4];
#pragma unroll
  for (int a = 0; a < 4; ++a)
#pragma unroll
    for (int c = 0; c < 4; ++c) acc[a][c] = Z4;

  for (int it = 0; it < 8; ++it) {
    int k0 = it << 6;
    __syncthreads();
#pragma unroll
    for (int i = 0; i < 4; ++i) {
      int g   = wv * 4 + i;
      int row = g * 8 + drow;
      ASYNC16(xb + (size_t)(m0 + row) * 512 + k0 + dchk * 8, &As[g * 512]);
    }
#pragma unroll
    for (int i = 0; i < 4; ++i) {
      int g   = wv * 4 + i;
      int row = g * 8 + drow;
      ASYNC16(W + (size_t)(n0 + row) * 512 + k0 + dchk * 8, &Bs[g * 512]);
    }
    __syncthreads();
#pragma unroll
    for (int kk = 0; kk < 2; ++kk) {
      s16x8 af[4], bfr[4];
#pragma unroll
      for (int rb = 0; rb < 4; ++rb) {
        int row = wr + rb * 16 + l16;
        int c   = kk * 4 + quad;
        af[rb] = *(const s16x8*)(As + row * 64 + ((c ^ (row & 7)) * 8));
      }
#pragma unroll
      for (int cb = 0; cb < 4; ++cb) {
        int row = wc + cb * 16 + l16;
        int c   = kk * 4 + quad;
        bfr[cb] = *(const s16x8*)(Bs + row * 64 + ((c ^ (row & 7)) * 8));
      }
#pragma unroll
      for (int rb = 0; rb < 4; ++rb)
#pragma unroll
        for (int cb = 0; cb < 4; ++cb)
          acc[rb][cb] = __builtin_amdgcn_mfma_f32_16x16x32_bf16(af[rb], bfr[cb], acc[rb][cb], 0, 0, 0);
    }
  }

  float bsv[4];
#pragma unroll
  for (int cb = 0; cb < 4; ++cb) bsv[cb] = bias[n0 + wc + cb * 16 + l16];

  if (mat < 2) {
    short* D = (mat == 0) ? Qg : Kg;
#pragma unroll
    for (int rb = 0; rb < 4; ++rb)
#pragma unroll
      for (int cb = 0; cb < 4; ++cb)
#pragma unroll
        for (int r = 0; r < 4; ++r) {
          int m = m0 + wr + rb * 16 + quad * 4 + r;
          D[(size_t)m * 512 + n0 + wc + cb * 16 + l16] =
              (short)f2bf(acc[rb][cb][r] + bsv[cb]);
        }
  } else {
    // V: tiled transpose layout [bb][e>>4][s>>5][e&15][s&31], 1KB tiles
#pragma unroll
    for (int rb = 0; rb < 4; ++rb)
#pragma unroll
      for (int cb = 0; cb < 4; ++cb) {
        u16x4 h;
#pragma unroll
        for (int r = 0; r < 4; ++r) h[r] = f2bf(acc[rb][cb][r] + bsv[cb]);
        int m  = m0 + wr + rb * 16 + quad * 4;
        int bb = m >> 11, sl = m & 2047;
        int e  = n0 + wc + cb * 16 + l16;
        size_t idx = ((((size_t)bb * 32 + (e >> 4)) * 64 + (sl >> 5)) * 16 +
                      (e & 15)) * 32 + (sl & 31);
        *(u16x4*)(VTg + idx) = h;
      }
  }
}

// ---------------- kernel 3: flash attention v5 ----------------
// 256 blocks (b=blk&7 -> XCD), 64 Q-rows/block, 8 waves, 64-key iterations.
// QK: wave (a=wv>>2, h=wv&3) computes rows [a*32,a*32+32) x keys [h*16,h*16+16):
//     each K-frag read once, used for TWO row-group MFMAs (sA,sB).
// PV: wave wv owns e-slice [wv*64, wv*64+64), all 64 rows, V read once per CU.
// LDS 74 KB: Kt 64 KB (single buffer, swizzled-source DMA), Pl 64x72, lred.
// Ledger (2 barriers / 64 keys):
//   top: issue vf0 (4 V loads, hidden under QK) -> QK reads Kt -> softmax -> Pl write
//   B1: V loads + Pl visible; Kt reads done
//   post-B1: issue K-DMA(it+1) -> Kt ; PV reads Pl + vf regs (vf1 issued mid-PV)
//   B2: K-DMA drained (implicit vmcnt 0); Pl WAR protected
__global__ __launch_bounds__(512, 2) void attn_kernel(
    const short* __restrict__ Qg, const short* __restrict__ Kg,
    const short* __restrict__ VTg, float* __restrict__ out) {
  __shared__ __align__(16) short Kt[64 * 512];   // 64 KB, [key][chunk^(key&7)]
  __shared__ __align__(16) short Pl[64 * 72];    // 9 KB, stride 72 shorts (144B)
  __shared__ float lred[4][64];
  const float SCL2 = 0.06375871855f;  // log2(e)/sqrt(512)

  int b = blockIdx.x & 7, qt = blockIdx.x >> 3;   // qt 0..31
  int s0 = qt << 6;                                // 64 rows/block
  int tid = threadIdx.x, lane = tid & 63, wv = tid >> 6;  // wv 0..7
  int l16 = lane & 15, quad = lane >> 4;
  int a = wv >> 2, h = wv & 3;                     // QK role: row-half / key-group
  int e0 = wv << 6;                                // PV role: 64-wide e slice

  const short* Kb = Kg  + (size_t)b * S_LEN * 512;
  const short* Vb = VTg + (size_t)b * 1048576;     // [32 et][64 st][16][32]

  // K DMA wave base (8 rows of 1KB per wave per iter; swizzled source)
  const short* kg0 = Kb + (size_t)(wv * 8) * 512;
  int klo = lane;                                  // dest chunk index 0..63

  // V fragment base: tile (et = wv*4+ec, st = it*2+kc); 1KB coalesced per load
  const short* vbase = Vb + (size_t)(wv * 4) * 32768 + l16 * 32 + quad * 8;

  // ---- prologue: stage K tile 0, load Q frags (32 rows in regs) ----
#pragma unroll
  for (int i = 0; i < 8; ++i)
    ASYNC16(kg0 + (size_t)i * 512 + ((klo ^ i) * 8), &Kt[(wv * 8 + i) * 512]);

  const short* qrowA = Qg + ((size_t)b * S_LEN + s0 + a * 32 + l16) * 512 + quad * 8;
  const short* qrowB = qrowA + (size_t)16 * 512;
  s16x8 qfA[16], qfB[16];
#pragma unroll
  for (int c = 0; c < 16; ++c) {
    qfA[c] = *(const s16x8*)(qrowA + c * 32);
    qfB[c] = *(const s16x8*)(qrowB + c * 32);
  }

  const f32x4 Z4 = {0.f, 0.f, 0.f, 0.f};
  f32x4 acc[4][4];   // [rowgroup g][e-chunk ec] -> AGPRs
#pragma unroll
  for (int g = 0; g < 4; ++g)
#pragma unroll
    for (int ec = 0; ec < 4; ++ec) acc[g][ec] = Z4;
  f32x4 lsumA = Z4, lsumB = Z4;

  __syncthreads();   // K tile 0 + Q frags drained

  for (int it = 0; it < 32; ++it) {
    // ---- V prefetch kc0 (consumed post-B1; latency hidden under QK) ----
    const short* vb_it = vbase + (size_t)(it * 2) * 512;
    s16x8 vf0[4];
#pragma unroll
    for (int ec = 0; ec < 4; ++ec)
      vf0[ec] = *(const s16x8*)(vb_it + (size_t)ec * 32768);

    // ---- QK: S[32 rows(a) x 16 keys(h)]; each kf used by 2 row-groups ----
    f32x4 sA = Z4, sB = Z4;
    int krow = h * 16 + l16;
    const short* kb = &Kt[krow * 512];
    int ksw = krow & 7;
#pragma unroll
    for (int c = 0; c < 16; ++c) {
      s16x8 kf = *(const s16x8*)(kb + (((c * 4 + quad) ^ ksw) * 8));
      sA = __builtin_amdgcn_mfma_f32_16x16x32_bf16(qfA[c], kf, sA, 0, 0, 0);
      sB = __builtin_amdgcn_mfma_f32_16x16x32_bf16(qfB[c], kf, sB, 0, 0, 0);
    }

    // ---- no-max softmax; write P (rows a*32.. / a*32+16..) ----
#pragma unroll
    for (int r = 0; r < 4; ++r) {
      float pA = exp2f(sA[r] * SCL2);
      lsumA[r] += pA;
      Pl[(a * 32 + quad * 4 + r) * 72 + h * 16 + l16] = (short)f2bf(pA);
      float pB = exp2f(sB[r] * SCL2);
      lsumB[r] += pB;
      Pl[(a * 32 + 16 + quad * 4 + r) * 72 + h * 16 + l16] = (short)f2bf(pB);
    }

    __syncthreads();   // B1: vf0 drained; Kt reads done; P visible

    // ---- stage K tile it+1 (Kt readers finished at B1) ----
    if (it + 1 < 32) {
      size_t adv = (size_t)(it + 1) * 32768;   // 64 keys * 512 shorts
#pragma unroll
      for (int i = 0; i < 8; ++i)
        ASYNC16(kg0 + adv + (size_t)i * 512 + ((klo ^ i) * 8),
                &Kt[(wv * 8 + i) * 512]);
    }

    // ---- PV kc0: O[64 x 64e] += P[64 x keys 0..31] @ V ----
    s16x8 pf[4];
#pragma unroll
    for (int g = 0; g < 4; ++g)
      pf[g] = *(const s16x8*)(&Pl[(g * 16 + l16) * 72 + quad * 8]);
#pragma unroll
    for (int ec = 0; ec < 4; ++ec)
#pragma unroll
      for (int g = 0; g < 4; ++g)
        acc[g][ec] = __builtin_amdgcn_mfma_f32_16x16x32_bf16(pf[g], vf0[ec], acc[g][ec], 0, 0, 0);

    // ---- PV kc1: keys 32..63 (vf1 issued here; partial latency accepted) ----
    s16x8 vf1[4];
    const short* vb1 = vb_it + 512;
#pragma unroll
    for (int ec = 0; ec < 4; ++ec)
      vf1[ec] = *(const s16x8*)(vb1 + (size_t)ec * 32768);
#pragma unroll
    for (int g = 0; g < 4; ++g)
      pf[g] = *(const s16x8*)(&Pl[(g * 16 + l16) * 72 + 32 + quad * 8]);
#pragma unroll
    for (int ec = 0; ec < 4; ++ec)
#pragma unroll
      for (int g = 0; g < 4; ++g)
        acc[g][ec] = __builtin_amdgcn_mfma_f32_16x16x32_bf16(pf[g], vf1[ec], acc[g][ec], 0, 0, 0);

    __syncthreads();   // B2: K-DMA drained; Pl WAR protected
  }

  // ---- epilogue: reduce row sums over keys (l16) then over 4 h-waves ----
#pragma unroll
  for (int r = 0; r < 4; ++r) {
    float vA = lsumA[r];
    vA += __shfl_xor(vA, 1); vA += __shfl_xor(vA, 2);
    vA += __shfl_xor(vA, 4); vA += __shfl_xor(vA, 8);
    lsumA[r] = vA;
    float vB = lsumB[r];
    vB += __shfl_xor(vB, 1); vB += __shfl_xor(vB, 2);
    vB += __shfl_xor(vB, 4); vB += __shfl_xor(vB, 8);
    lsumB[r] = vB;
  }
  if (l16 == 0) {
#pragma unroll
    for (int r = 0; r < 4; ++r) {
      lred[h][a * 32 + quad * 4 + r]      = lsumA[r];
      lred[h][a * 32 + 16 + quad * 4 + r] = lsumB[r];
    }
  }
  __syncthreads();
  if (tid < 64) {
    float t = lred[0][tid] + lred[1][tid] + lred[2][tid] + lred[3][tid];
    lred[0][tid] = 1.0f / t;
  }
  __syncthreads();

  // ---- store: acc[g][ec][r] = O[g*16+quad*4+r][e0+ec*16+l16] ----
  float* ob = out + ((size_t)b * S_LEN + s0) * 512 + e0;
#pragma unroll
  for (int g = 0; g < 4; ++g)
#pragma unroll
    for (int r = 0; r < 4; ++r) {
      float li = lred[0][g * 16 + quad * 4 + r];
#pragma unroll
      for (int ec = 0; ec < 4; ++ec)
        ob[(size_t)(g * 16 + quad * 4 + r) * 512 + ec * 16 + l16] =
            acc[g][ec][r] * li;
    }
}

// ---------------- host launch ----------------
extern "C" void kernel_launch(void* const* d_in, const int* in_sizes, int n_in,
                              void* d_out, int out_size, void* d_ws, size_t ws_size,
                              hipStream_t stream) {
  const float* x  = (const float*)d_in[0];
  const float* Wq = (const float*)d_in[1];
  const float* bq = (const float*)d_in[2];
  const float* Wk = (const float*)d_in[3];
  const float* bk = (const float*)d_in[4];
  const float* Wv = (const float*)d_in[5];
  const float* bv = (const float*)d_in[6];

  short* Wt  = (short*)d_ws;
  short* xb  = (short*)((char*)d_ws + 1572864);
  short* Qg  = xb + (size_t)8388608;
  short* Kg  = Qg + (size_t)8388608;
  short* VTg = Kg + (size_t)8388608;

  xconv_kernel<<<4096, 256, 0, stream>>>(x, xb);
  wconv_kernel<<<192, 256, 0, stream>>>(Wq, Wk, Wv, Wt);
  qkv_gemm<<<1536, 256, 0, stream>>>(xb, Wt, bq, bk, bv, Qg, Kg, VTg);
  attn_kernel<<<256, 512, 0, stream>>>(Qg, Kg, VTg, (float*)d_out);
}

// Round 5
// 240.170 us; speedup vs baseline: 1.2327x; 1.1022x over previous
//
#include <hip/hip_runtime.h>
#include <stdint.h>

// Self-attention, B=8 S=2048 D=E=512, fp32 in/out, bf16 MFMA internally.
//   xconv:    x fp32 -> bf16
//   wconv:    W[k][n] fp32 -> Wt[n][k] bf16 (x3), LDS-tiled transpose
//   qkv_gemm: m97-style async-staged GEMM; Q,K row-major bf16; V in 16e x 32s
//             1KB-tiled transposed layout [B][E/16][S/32][16][32] bf16
//   attn v6:  v3 wave layout, NEW sync structure (T3/T4/T5):
//             Kt TRIPLE-buffered (DMA has 2 full iters to land), Pl double-buffered,
//             ONE barrier/iter as fused asm "s_waitcnt vmcnt(8) lgkmcnt(0); s_barrier"
//             -> V(kt)+D(kt+2) stay in flight ACROSS the barrier; never vmcnt(0).
//             s_setprio(1) around MFMA clusters.

using f32x4 = __attribute__((ext_vector_type(4))) float;
using s16x8 = __attribute__((ext_vector_type(8))) short;
using u16x4 = __attribute__((ext_vector_type(4))) unsigned short;

#define S_LEN 2048
#define EMB   512

#define ASYNC16(g, l)                                                     \
  __builtin_amdgcn_global_load_lds(                                       \
      (const __attribute__((address_space(1))) void*)(g),                 \
      (__attribute__((address_space(3))) void*)(l), 16, 0, 0)

__device__ __forceinline__ unsigned short f2bf(float f) {
  union { float f; unsigned u; } v; v.f = f;
  unsigned r = v.u + 0x7fffu + ((v.u >> 16) & 1u);   // RNE
  return (unsigned short)(r >> 16);
}

// ---------------- kernel 0: x fp32 -> bf16 ----------------
__global__ __launch_bounds__(256) void xconv_kernel(
    const float* __restrict__ x, short* __restrict__ xb) {
  int i = (blockIdx.x * 256 + threadIdx.x) * 8;
  f32x4 a = *(const f32x4*)(x + i);
  f32x4 b = *(const f32x4*)(x + i + 4);
  s16x8 h;
  h[0] = (short)f2bf(a[0]); h[1] = (short)f2bf(a[1]);
  h[2] = (short)f2bf(a[2]); h[3] = (short)f2bf(a[3]);
  h[4] = (short)f2bf(b[0]); h[5] = (short)f2bf(b[1]);
  h[6] = (short)f2bf(b[2]); h[7] = (short)f2bf(b[3]);
  *(s16x8*)(xb + i) = h;
}

// ---------------- kernel 1: weight transpose (LDS-tiled, coalesced) ----------------
__global__ __launch_bounds__(256) void wconv_kernel(
    const float* __restrict__ Wq, const float* __restrict__ Wk,
    const float* __restrict__ Wv, short* __restrict__ Wt) {
  __shared__ float T[64][65];
  int bid = blockIdx.x;
  int mat = bid >> 6;
  int t   = bid & 63;
  int k0  = (t & 7) << 6, n0 = (t >> 3) << 6;
  const float* W = (mat == 0) ? Wq : (mat == 1) ? Wk : Wv;
  int tid = threadIdx.x;
  int rr = tid >> 4, cc = tid & 15;
#pragma unroll
  for (int p = 0; p < 4; ++p) {
    int row = p * 16 + rr;
    f32x4 v = *(const f32x4*)(W + (size_t)(k0 + row) * 512 + n0 + cc * 4);
#pragma unroll
    for (int j = 0; j < 4; ++j) T[row][cc * 4 + j] = v[j];
  }
  __syncthreads();
  short* D = Wt + (size_t)mat * 262144;
#pragma unroll
  for (int p = 0; p < 4; ++p) {
    int nrow = p * 16 + rr;
    u16x4 h;
#pragma unroll
    for (int j = 0; j < 4; ++j) h[j] = f2bf(T[cc * 4 + j][nrow]);
    *(u16x4*)(D + (size_t)(n0 + nrow) * 512 + k0 + cc * 4) = h;
  }
}

// ---------------- kernel 2: QKV projection GEMM (m97 structure) ----------------
__global__ __launch_bounds__(256) void qkv_gemm(
    const short* __restrict__ xb, const short* __restrict__ Wt,
    const float* __restrict__ bq, const float* __restrict__ bk,
    const float* __restrict__ bv,
    short* __restrict__ Qg, short* __restrict__ Kg, short* __restrict__ VTg) {
  __shared__ __align__(16) short As[128 * 64];   // 16B chunk c stored at c^(row&7)
  __shared__ __align__(16) short Bs[128 * 64];
  int gid = blockIdx.x;
  int mat = gid >> 9;
  int rem = gid & 511;
  int mt  = rem & 127, nt = rem >> 7;
  int m0  = mt << 7,   n0 = nt << 7;
  const short* W    = Wt + (size_t)mat * 262144;
  const float* bias = (mat == 0) ? bq : (mat == 1) ? bk : bv;

  int tid = threadIdx.x, lane = tid & 63, wv = tid >> 6;
  int l16 = lane & 15, quad = lane >> 4;
  int wr = (wv & 1) << 6, wc = (wv >> 1) << 6;
  int drow = lane >> 3;
  int dchk = (lane & 7) ^ drow;

  const f32x4 Z4 = {0.f, 0.f, 0.f, 0.f};
  f32x4 acc[4][4];
#pragma unroll
  for (int a = 0; a < 4; ++a)
#pragma unroll
    for (int c = 0; c < 4; ++c) acc[a][c] = Z4;

  for (int it = 0; it < 8; ++it) {
    int k0 = it << 6;
    __syncthreads();
#pragma unroll
    for (int i = 0; i < 4; ++i) {
      int g   = wv * 4 + i;
      int row = g * 8 + drow;
      ASYNC16(xb + (size_t)(m0 + row) * 512 + k0 + dchk * 8, &As[g * 512]);
    }
#pragma unroll
    for (int i = 0; i < 4; ++i) {
      int g   = wv * 4 + i;
      int row = g * 8 + drow;
      ASYNC16(W + (size_t)(n0 + row) * 512 + k0 + dchk * 8, &Bs[g * 512]);
    }
    __syncthreads();
#pragma unroll
    for (int kk = 0; kk < 2; ++kk) {
      s16x8 af[4], bfr[4];
#pragma unroll
      for (int rb = 0; rb < 4; ++rb) {
        int row = wr + rb * 16 + l16;
        int c   = kk * 4 + quad;
        af[rb] = *(const s16x8*)(As + row * 64 + ((c ^ (row & 7)) * 8));
      }
#pragma unroll
      for (int cb = 0; cb < 4; ++cb) {
        int row = wc + cb * 16 + l16;
        int c   = kk * 4 + quad;
        bfr[cb] = *(const s16x8*)(Bs + row * 64 + ((c ^ (row & 7)) * 8));
      }
#pragma unroll
      for (int rb = 0; rb < 4; ++rb)
#pragma unroll
        for (int cb = 0; cb < 4; ++cb)
          acc[rb][cb] = __builtin_amdgcn_mfma_f32_16x16x32_bf16(af[rb], bfr[cb], acc[rb][cb], 0, 0, 0);
    }
  }

  float bsv[4];
#pragma unroll
  for (int cb = 0; cb < 4; ++cb) bsv[cb] = bias[n0 + wc + cb * 16 + l16];

  if (mat < 2) {
    short* D = (mat == 0) ? Qg : Kg;
#pragma unroll
    for (int rb = 0; rb < 4; ++rb)
#pragma unroll
      for (int cb = 0; cb < 4; ++cb)
#pragma unroll
        for (int r = 0; r < 4; ++r) {
          int m = m0 + wr + rb * 16 + quad * 4 + r;
          D[(size_t)m * 512 + n0 + wc + cb * 16 + l16] =
              (short)f2bf(acc[rb][cb][r] + bsv[cb]);
        }
  } else {
    // V: tiled transpose layout [bb][e>>4][s>>5][e&15][s&31], 1KB tiles
#pragma unroll
    for (int rb = 0; rb < 4; ++rb)
#pragma unroll
      for (int cb = 0; cb < 4; ++cb) {
        u16x4 h;
#pragma unroll
        for (int r = 0; r < 4; ++r) h[r] = f2bf(acc[rb][cb][r] + bsv[cb]);
        int m  = m0 + wr + rb * 16 + quad * 4;
        int bb = m >> 11, sl = m & 2047;
        int e  = n0 + wc + cb * 16 + l16;
        size_t idx = ((((size_t)bb * 32 + (e >> 4)) * 64 + (sl >> 5)) * 16 +
                      (e & 15)) * 32 + (sl & 31);
        *(u16x4*)(VTg + idx) = h;
      }
  }
}

// ---------------- kernel 3: flash attention v6 (counted-vmcnt pipeline) ----------------
// 256 blocks (b=blk&7 -> XCD), 64 Q-rows/block, 8 waves, 1 block/CU, LDS ~108 KB.
// QK wave (a=wv&3: 16-row group, h=wv>>2: 16-key half); PV wave: e-slice wv*64.
// Per-iter op schedule (per wave):
//   top:  issue V(kt) x4 (global->reg)  |  issue D(kt+2) x4 (DMA -> Kt[wbuf])
//   QK(kt) reads Kt[rbuf]; softmax -> Pl[kt&1]
//   asm: s_waitcnt vmcnt(8) lgkmcnt(0); s_barrier     <- retires D(kt+1) only;
//        V(kt)+D(kt+2) (8 ops) stay IN FLIGHT across the barrier
//   PV(kt) reads Pl[kt&1] + vf regs (compiler waits vmcnt(4) -> D(kt+2) survives)
// Ledger: Kt RAW: D(kt) older than V(kt-1) => retired at barrier(kt-1) block-wide,
//   QK(kt) is post-barrier(kt-1) for all waves. Kt WAR: D(kt+2) issued post-
//   barrier(kt-1); last reader QK(kt-1) pre-barrier(kt-1). P RAW: lgkm+barrier.
//   P WAR: Pl double-buffered; barrier(kt+1) separates PV(kt) from SM(kt+2).
//   D-issue wraps (kt+2)&63 so barrier count is uniform (tail prefetch harmless).
__global__ __launch_bounds__(512, 2) void attn_kernel(
    const short* __restrict__ Qg, const short* __restrict__ Kg,
    const short* __restrict__ VTg, float* __restrict__ out) {
  __shared__ __align__(16) short Kt[3][32 * 512];   // 96 KB triple buffer
  __shared__ __align__(16) short Pl[2][64 * 40];    // 10 KB double buffer
  __shared__ float l_l[64];
  const float SCL2 = 0.06375871855f;  // log2(e)/sqrt(512)

  int b = blockIdx.x & 7, qt = blockIdx.x >> 3;   // qt 0..31
  int s0 = qt << 6;                                // 64 rows/block
  int tid = threadIdx.x, lane = tid & 63, wv = tid >> 6;  // wv 0..7
  int l16 = lane & 15, quad = lane >> 4;
  int a = wv & 3, h = wv >> 2;
  int e0 = wv << 6;

  const short* Kb = Kg  + (size_t)b * S_LEN * 512;
  const short* Vb = VTg + (size_t)b * 1048576;     // [32 et][64 st][16][32]

  // K DMA per-lane source addresses (1 row = 1KB per op, chunk-swizzled src)
  const short* kdma[4];
#pragma unroll
  for (int i = 0; i < 4; ++i) {
    int r = wv * 4 + i;
    kdma[i] = Kb + (size_t)r * 512 + ((lane ^ (r & 7)) * 8);
  }
  // V fragment base: tile (et = wv*4+cb, st = kt); 1KB coalesced per load
  const short* vbase = Vb + (size_t)wv * 131072 + l16 * 32 + quad * 8;

  // ---- prologue: stage K tiles 0,1 into Kt[0],Kt[1]; load Q frags ----
#pragma unroll
  for (int i = 0; i < 4; ++i)
    ASYNC16(kdma[i], &Kt[0][(wv * 4 + i) * 512]);
#pragma unroll
  for (int i = 0; i < 4; ++i)
    ASYNC16(kdma[i] + 16384, &Kt[1][(wv * 4 + i) * 512]);

  const short* qrow = Qg + ((size_t)b * S_LEN + s0 + a * 16 + l16) * 512 + quad * 8;
  s16x8 qf[16];
#pragma unroll
  for (int kk = 0; kk < 16; ++kk) qf[kk] = *(const s16x8*)(qrow + kk * 32);

  const f32x4 Z4 = {0.f, 0.f, 0.f, 0.f};
  f32x4 acc[4][4];
#pragma unroll
  for (int rb = 0; rb < 4; ++rb)
#pragma unroll
    for (int cb = 0; cb < 4; ++cb) acc[rb][cb] = Z4;
  f32x4 lsum = Z4;

  __syncthreads();   // prologue full drain (one-time): K0,K1 + Q landed

  int rbuf = 0, wbuf = 2;
  for (int kt = 0; kt < 64; ++kt) {
    // ---- issue V(kt) (global->reg, coalesced 1KB/wave) ----
    s16x8 vf[4];
#pragma unroll
    for (int cb = 0; cb < 4; ++cb)
      vf[cb] = *(const s16x8*)(vbase + (size_t)cb * 32768 + (size_t)kt * 512);
    __builtin_amdgcn_sched_barrier(0);   // pin V-before-D (keeps CW at vmcnt(4))

    // ---- issue K-DMA(kt+2) -> Kt[wbuf] (2 full iters to land; wraps at tail) ----
    {
      size_t adv = (size_t)((kt + 2) & 63) * 16384;
#pragma unroll
      for (int i = 0; i < 4; ++i)
        ASYNC16(kdma[i] + adv, &Kt[wbuf][(wv * 4 + i) * 512]);
    }
    __builtin_amdgcn_sched_barrier(0);

    // ---- QK: S[16 rows(a) x 16 keys(h)] from Kt[rbuf] ----
    f32x4 s_a = Z4, s_b = Z4;
    int krow = h * 16 + l16;
    const short* kb = &Kt[rbuf][krow * 512];
    int ksw = krow & 7;
    __builtin_amdgcn_s_setprio(1);
#pragma unroll
    for (int kk = 0; kk < 8; ++kk) {
      s16x8 kf0 = *(const s16x8*)(kb + (((2 * kk) * 4 + quad) ^ ksw) * 8);
      s_a = __builtin_amdgcn_mfma_f32_16x16x32_bf16(qf[2 * kk], kf0, s_a, 0, 0, 0);
      s16x8 kf1 = *(const s16x8*)(kb + (((2 * kk + 1) * 4 + quad) ^ ksw) * 8);
      s_b = __builtin_amdgcn_mfma_f32_16x16x32_bf16(qf[2 * kk + 1], kf1, s_b, 0, 0, 0);
    }
    __builtin_amdgcn_s_setprio(0);
    f32x4 sv = s_a + s_b;

    // ---- no-max softmax -> Pl[kt&1] ----
    short* Pc = Pl[kt & 1];
#pragma unroll
    for (int r = 0; r < 4; ++r) {
      float p = exp2f(sv[r] * SCL2);
      lsum[r] += p;
      Pc[(a * 16 + quad * 4 + r) * 40 + h * 16 + l16] = (short)f2bf(p);
    }

    // ---- fused counted drain + barrier (NEVER vmcnt(0) in loop) ----
    // retires D(kt+1) (oldest); keeps V(kt)x4 + D(kt+2)x4 in flight.
    asm volatile("s_waitcnt vmcnt(8) lgkmcnt(0)\n\ts_barrier" ::: "memory");

    // ---- PV: O[64 x 64e] += P[64x32] @ V[32 x 64e] ----
    s16x8 pf[4];
#pragma unroll
    for (int g = 0; g < 4; ++g)
      pf[g] = *(const s16x8*)(Pc + (g * 16 + l16) * 40 + quad * 8);
    __builtin_amdgcn_s_setprio(1);
#pragma unroll
    for (int cb = 0; cb < 4; ++cb)
#pragma unroll
      for (int g = 0; g < 4; ++g)
        acc[g][cb] = __builtin_amdgcn_mfma_f32_16x16x32_bf16(pf[g], vf[cb], acc[g][cb], 0, 0, 0);
    __builtin_amdgcn_s_setprio(0);

    rbuf = (rbuf == 2) ? 0 : rbuf + 1;
    wbuf = (wbuf == 2) ? 0 : wbuf + 1;
  }

  // ---- epilogue: combine row sums (h halves), divide, store fp32 ----
#pragma unroll
  for (int r = 0; r < 4; ++r) {
    float v = lsum[r];
    v += __shfl_xor(v, 1);
    v += __shfl_xor(v, 2);
    v += __shfl_xor(v, 4);
    v += __shfl_xor(v, 8);
    lsum[r] = v;                    // sum over this wave's 16-key half
  }
  if (h == 0 && l16 == 0) {
#pragma unroll
    for (int r = 0; r < 4; ++r) l_l[a * 16 + quad * 4 + r] = lsum[r];
  }
  __syncthreads();
  if (h == 1 && l16 == 0) {
#pragma unroll
    for (int r = 0; r < 4; ++r) l_l[a * 16 + quad * 4 + r] += lsum[r];
  }
  __syncthreads();

#pragma unroll
  for (int rb = 0; rb < 4; ++rb) {
    f32x4 lv = *(const f32x4*)(l_l + rb * 16 + quad * 4);
    f32x4 li;
#pragma unroll
    for (int r = 0; r < 4; ++r) li[r] = 1.0f / lv[r];
#pragma unroll
    for (int cb = 0; cb < 4; ++cb)
#pragma unroll
      for (int r = 0; r < 4; ++r)
        out[((size_t)b * S_LEN + s0 + rb * 16 + quad * 4 + r) * 512 + e0 + cb * 16 + l16] =
            acc[rb][cb][r] * li[r];
  }
}

// ---------------- host launch ----------------
extern "C" void kernel_launch(void* const* d_in, const int* in_sizes, int n_in,
                              void* d_out, int out_size, void* d_ws, size_t ws_size,
                              hipStream_t stream) {
  const float* x  = (const float*)d_in[0];
  const float* Wq = (const float*)d_in[1];
  const float* bq = (const float*)d_in[2];
  const float* Wk = (const float*)d_in[3];
  const float* bk = (const float*)d_in[4];
  const float* Wv = (const float*)d_in[5];
  const float* bv = (const float*)d_in[6];

  short* Wt  = (short*)d_ws;
  short* xb  = (short*)((char*)d_ws + 1572864);
  short* Qg  = xb + (size_t)8388608;
  short* Kg  = Qg + (size_t)8388608;
  short* VTg = Kg + (size_t)8388608;

  xconv_kernel<<<4096, 256, 0, stream>>>(x, xb);
  wconv_kernel<<<192, 256, 0, stream>>>(Wq, Wk, Wv, Wt);
  qkv_gemm<<<1536, 256, 0, stream>>>(xb, Wt, bq, bk, bv, Qg, Kg, VTg);
  attn_kernel<<<256, 512, 0, stream>>>(Qg, Kg, VTg, (float*)d_out);
}